// Round 8
// baseline (261.902 us; speedup 1.0000x reference)
//
#include <hip/hip_runtime.h>

namespace {

typedef __attribute__((ext_vector_type(8)))  short          short8;
typedef __attribute__((ext_vector_type(8)))  unsigned short u16x8;
typedef __attribute__((ext_vector_type(4)))  unsigned short u16x4;
typedef __attribute__((ext_vector_type(4)))  float          f32x4;
typedef __attribute__((ext_vector_type(8)))  _Float16       half8;
typedef __attribute__((ext_vector_type(4)))  _Float16       half4;
typedef __attribute__((ext_vector_type(2)))  _Float16       half2_t;

constexpr int V  = 200;
constexpr int F  = 64;
constexpr int NT = 512;   // N*T
constexpr int VP = 208;   // 13 x 16

// ---- ws layout (bytes) ----
// Mc  : f16 [512][13 tile][7 kt][64 lane][8]  = 47,710,208  (m = min(S,S^T), frag order)
// xTf : f16 [512][7 kt][4 ft][64 lane][8]     = 14,680,064  (x^T fragments)
// attF: f16 [8][13 tile][7 kt][64 lane][8]    =    745,472  (Att[u][v] fragments, 0 on diag)
// thT : ushort bf16 [3][64][64]               =     24,576
// sdg : f32 [512][208]  S[v][v]               =    425,984
// adg : f32 [8][208]    Att[v][v]             =      6,656
constexpr size_t WS_MC   = 0;
constexpr size_t WS_XTF  = 47710208;
constexpr size_t WS_ATTF = 62390272;
constexpr size_t WS_THT  = 63135744;
constexpr size_t WS_SD   = 63160320;
constexpr size_t WS_ADG  = 63586304;   // end 63,592,960

__device__ __forceinline__ unsigned short f2bf(float x) {
    union { float f; unsigned u; } c; c.f = x;
    unsigned r = c.u + 0x7FFF + ((c.u >> 16) & 1);
    return (unsigned short)(r >> 16);
}

// ============ P: merged prep, b-batched x8 — grid (64, 29) ============
// y < 28 : tile-pair (ti<=tj); Att tiles LDS-resident; loops b = 8bx..8bx+7
//          with S-tile register prefetch. Writes Mc fragments (+sdiag on diag;
//          attF/adiag once per n).
// y == 28: xTf fragments for b = 8bx..8bx+7; bx==0 additionally thT.
__global__ __launch_bounds__(256)
void prep_all(const float* __restrict__ S,
              const float* __restrict__ Att,
              const float* __restrict__ x,
              const float* __restrict__ Theta,
              _Float16* __restrict__ Mc,
              _Float16* __restrict__ attF,
              _Float16* __restrict__ xTf,
              unsigned short* __restrict__ thT,
              float* __restrict__ sdiag,
              float* __restrict__ adiag)
{
    __shared__ __align__(16) char smem[30464];
    const int bx = blockIdx.x, tid = threadIdx.x;

    if (blockIdx.y == 28) {
        // ---- xTf path: 8 b's ----
        _Float16* xs = (_Float16*)smem;    // [224][68] f16
        for (int i = 0; i < 8; ++i) {
            const int b = 8 * bx + i;
            const float* __restrict__ xp = x + (size_t)b * (V * F);
            __syncthreads();               // prev b's transpose reads done
            for (int idx = tid; idx < 224 * 16; idx += 256) {
                const int u = idx >> 4, fg = idx & 15;
                half4 w = (half4)(_Float16)0.f;
                if (u < V) {
                    const float4 v4 = *(const float4*)&xp[u * F + 4 * fg];
                    w[0] = (_Float16)v4.x; w[1] = (_Float16)v4.y;
                    w[2] = (_Float16)v4.z; w[3] = (_Float16)v4.w;
                }
                *(half4*)&xs[u * 68 + 4 * fg] = w;
            }
            __syncthreads();
            // frag = kt*4+ft; lane holds x[u=32kt+8q+j][f=16ft+ln]
            _Float16* xo = xTf + (size_t)b * 14336;
            for (int it = 0; it < 7; ++it) {
                const int wid = tid + 256 * it;            // 0..1791
                const int frag = wid >> 6, lane = wid & 63;
                const int kt = frag >> 2, ft = frag & 3;
                const int q = lane >> 4, ln = lane & 15;
                half8 w;
                #pragma unroll
                for (int j = 0; j < 8; ++j)
                    w[j] = xs[(32 * kt + 8 * q + j) * 68 + 16 * ft + ln];
                *(half8*)&xo[frag * 512 + lane * 8] = w;
            }
        }
        if (bx == 0) {
            float* T = (float*)smem;                       // [64][65] f32
            for (int k = 0; k < 3; ++k) {
                __syncthreads();
                for (int idx = tid; idx < 4096; idx += 256)
                    T[(idx >> 6) * 65 + (idx & 63)] = Theta[k * 4096 + idx];
                __syncthreads();
                for (int idx = tid; idx < 4096; idx += 256) {
                    const int fo = idx >> 6, f = idx & 63;
                    thT[k * 4096 + fo * 64 + f] = f2bf(T[f * 65 + fo]);
                }
            }
        }
        return;
    }

    // ---- tile-pair path ----
    float (*As)[33] = (float(*)[33])smem;                 // S  [ti-rows][tj-cols]
    float (*Bs)[33] = (float(*)[33])(smem + 4224);        // S  [tj-rows][ti-cols]
    float (*Ts)[33] = (float(*)[33])(smem + 8448);        // Att[ti-rows][tj-cols]
    float (*Us)[33] = (float(*)[33])(smem + 12672);       // Att[tj-rows][ti-cols] (ends 16,896)

    int rem = blockIdx.y, ti = 0;
    while (rem >= 7 - ti) { rem -= 7 - ti; ++ti; }
    const int tj = ti + rem;
    const bool diag = (ti == tj);

    const int n = bx >> 3;
    const float* __restrict__ Ap = Att + (size_t)n * (V * V);
    const int r = tid >> 3, cg = tid & 7, c0 = 4 * cg;

    // Att tiles once (same n for all 8 b's)
    {
        const int gr = 32 * ti + r, gc = 32 * tj + c0;
        float4 t = make_float4(0.f, 0.f, 0.f, 0.f);
        if (gr < V && gc < V) t = *(const float4*)&Ap[gr * V + gc];
        Ts[r][c0+0] = t.x; Ts[r][c0+1] = t.y; Ts[r][c0+2] = t.z; Ts[r][c0+3] = t.w;
        if (!diag) {
            const int hr = 32 * tj + r, hc = 32 * ti + c0;
            float4 uu = make_float4(0.f, 0.f, 0.f, 0.f);
            if (hr < V && hc < V) uu = *(const float4*)&Ap[hr * V + hc];
            Us[r][c0+0] = uu.x; Us[r][c0+1] = uu.y; Us[r][c0+2] = uu.z; Us[r][c0+3] = uu.w;
        }
    }

    // S-tile register prefetch
    float4 pa, pb;
    auto loadS = [&](int b) {
        const float* __restrict__ Sp = S + (size_t)b * (V * V);
        const int gr = 32 * ti + r, gc = 32 * tj + c0;
        pa = make_float4(0.f, 0.f, 0.f, 0.f);
        if (gr < V && gc < V) pa = *(const float4*)&Sp[gr * V + gc];
        if (!diag) {
            const int hr = 32 * tj + r, hc = 32 * ti + c0;
            pb = make_float4(0.f, 0.f, 0.f, 0.f);
            if (hr < V && hc < V) pb = *(const float4*)&Sp[hr * V + hc];
        }
    };
    loadS(8 * bx);

    // fragment thread mapping (constant across b)
    const int jh = tid & 1, lane = (tid >> 1) & 63, sub = tid >> 7;
    const int rr = lane & 15, qq = lane >> 4;
    const int vl = sub * 16 + rr;          // 0..31 within the 32-row block
    const int ub2 = 8 * qq + 4 * jh;       // u_local base

    #pragma unroll 1
    for (int i = 0; i < 8; ++i) {
        const int b = 8 * bx + i;
        // prefetched S tiles -> LDS
        As[r][c0+0] = pa.x; As[r][c0+1] = pa.y; As[r][c0+2] = pa.z; As[r][c0+3] = pa.w;
        if (!diag) {
            Bs[r][c0+0] = pb.x; Bs[r][c0+1] = pb.y; Bs[r][c0+2] = pb.z; Bs[r][c0+3] = pb.w;
        }
        __syncthreads();                   // tiles ready (Att too on i=0)
        if (i < 7) loadS(b + 1);           // next b's loads in flight over compute

        if (diag && cg == 0) {             // S diag + Att diag files
            const int vg = 32 * ti + r;
            if (vg < VP) {
                sdiag[b * VP + vg] = As[r][r];          // 0 for vg>=200 (padded)
                if ((b & 63) == 0) adiag[n * VP + vg] = Ts[r][r];
            }
        }

        const bool wAtt = ((b & 63) == 0);
        // orientation 1: v in ti-block (tiles 2ti+sub), kt = tj
        if (2 * ti + sub < 13) {
            half4 wm, wa;
            #pragma unroll
            for (int e = 0; e < 4; ++e) {
                const int ul = ub2 + e;
                const float mB = diag ? As[ul][vl] : Bs[ul][vl];
                wm[e] = (_Float16)fminf(As[vl][ul], mB);
                const float att = diag ? Ts[ul][vl] : Us[ul][vl];   // Att[u][v]
                wa[e] = (diag && ul == vl) ? (_Float16)0.f : (_Float16)att;
            }
            const size_t base = ((size_t)(b * 13 + 2 * ti + sub) * 7 + tj) * 512 + lane * 8 + jh * 4;
            *(half4*)&Mc[base] = wm;
            if (wAtt) {
                const size_t ab = ((size_t)(n * 13 + 2 * ti + sub) * 7 + tj) * 512 + lane * 8 + jh * 4;
                *(half4*)&attF[ab] = wa;
            }
        }
        // mirror: v in tj-block (tiles 2tj+sub), kt = ti
        if (!diag && 2 * tj + sub < 13) {
            half4 wm, wa;
            #pragma unroll
            for (int e = 0; e < 4; ++e) {
                const int ul = ub2 + e;
                wm[e] = (_Float16)fminf(Bs[vl][ul], As[ul][vl]);   // min(S[v'][u'],S[u'][v'])
                wa[e] = (_Float16)Ts[ul][vl];                      // Att[u'][v'], u'!=v'
            }
            const size_t base = ((size_t)(b * 13 + 2 * tj + sub) * 7 + ti) * 512 + lane * 8 + jh * 4;
            *(half4*)&Mc[base] = wm;
            if (wAtt) {
                const size_t ab = ((size_t)(n * 13 + 2 * tj + sub) * 7 + ti) * 512 + lane * 8 + jh * 4;
                *(half4*)&attF[ab] = wa;
            }
        }
        __syncthreads();                   // LDS reads done before next i overwrites
    }
}

// ============ G: streaming MFMA kernel — d computed on the fly ============
// grid 1024 (XCD-swizzled pairs). Per block: 7 (h=0) / 6 (h=1) v-tiles.
// xTf staged to LDS once; m fragments stream from HBM (double-buffered regs);
// att fragments from L2. a1=-m*att, a2=2m^2*att in packed f16 -> MFMA f16.
// d[v] = sum of streamed m (pk_add tree + shfl_xor over q); c = d-1-S_vv.
__global__ __launch_bounds__(256, 4)
void cheb_stream(const float* __restrict__ x,
                 const _Float16* __restrict__ Mc,
                 const _Float16* __restrict__ attF,
                 const float* __restrict__ sdiag,
                 const float* __restrict__ adiag,
                 const unsigned short* __restrict__ thT,
                 const _Float16* __restrict__ xTf,
                 float* __restrict__ out)
{
    __shared__ __align__(16) char smem[30080];
    _Float16*       xTs = (_Float16*)smem;                  // 28,672 B (K loop)
    unsigned short* ys  = (unsigned short*)smem;            // [112][72] = 16,128 (epi)
    unsigned short* ThS = (unsigned short*)(smem + 16128);  // [64][72]  =  9,216 (epi)
    float* dbuf = (float*)(smem + 28672);                   // [112] c = d-1-S_vv
    float* adb  = (float*)(smem + 29120);                   // [112] Att[v][v]
    float* sdb  = (float*)(smem + 29568);                   // [112] S[v][v]

    const int tid = threadIdx.x;
    const int ub_ = blockIdx.x;
    const int h   = (ub_ >> 3) & 1;
    const int b   = (ub_ & 7) | ((ub_ >> 4) << 3);
    const int n   = b >> 6;
    const int v0  = h * 112;

    // stage xTf -> LDS (coalesced, once)
    const _Float16* __restrict__ xfp = xTf + (size_t)b * 14336;
    #pragma unroll
    for (int it = 0; it < 7; ++it) {
        const int o = it * 2048 + tid * 8;
        *(half8*)&xTs[o] = *(const half8*)&xfp[o];
    }
    if (tid < 112) {
        const int gv = v0 + tid;
        adb[tid] = (gv < VP) ? adiag[n * VP + gv] : 0.f;
        sdb[tid] = (gv < VP) ? sdiag[b * VP + gv] : 0.f;
    }

    const int wave = tid >> 6, lane = tid & 63, q = lane >> 4, ln = lane & 15;
    int myBase, myCnt;
    if (h == 0) { myCnt = (wave < 3) ? 2 : 1; myBase = 2 * wave; }
    else        { myCnt = (wave < 2) ? 2 : 1; myBase = (wave < 2) ? 2 * wave : 2 + wave; }

    const float* __restrict__ xp = x + (size_t)b * (V * F);
    float* __restrict__ op = out + (size_t)b * (V * F);

    f32x4 acc1[2][4], acc2[2][4];
    #pragma unroll
    for (int i = 0; i < 2; ++i)
        #pragma unroll
        for (int j = 0; j < 4; ++j) { acc1[i][j] = (f32x4)0.f; acc2[i][j] = (f32x4)0.f; }

    // fragment bases (f16 element index at kt=0); tiles are 7*512 apart
    const size_t fb0 = ((size_t)(b * 13 + 7 * h + myBase) * 7) * 512 + lane * 8;
    const size_t fb1 = fb0 + 7 * 512;
    const size_t af0 = ((size_t)(n * 13 + 7 * h + myBase) * 7) * 512 + lane * 8;
    const size_t af1 = af0 + 7 * 512;

    half8 mc[2] = {}, ac[2] = {}, mn[2] = {}, an[2] = {};
    mc[0] = *(const half8*)&Mc[fb0];
    ac[0] = *(const half8*)&attF[af0];
    if (myCnt > 1) {
        mc[1] = *(const half8*)&Mc[fb1];
        ac[1] = *(const half8*)&attF[af1];
    }
    __syncthreads();   // xTs/adb/sdb ready

    float dsum0 = 0.f, dsum1 = 0.f;
    auto hsum = [](half8 m) -> float {
        const half2_t a = __builtin_shufflevector(m, m, 0, 1) + __builtin_shufflevector(m, m, 2, 3);
        const half2_t c = __builtin_shufflevector(m, m, 4, 5) + __builtin_shufflevector(m, m, 6, 7);
        const half2_t s = a + c;
        return (float)s[0] + (float)s[1];
    };

    #pragma unroll 1
    for (int kt = 0; kt < 7; ++kt) {
        if (kt < 6) {
            const size_t o = (size_t)(kt + 1) * 512;
            mn[0] = *(const half8*)&Mc[fb0 + o];
            an[0] = *(const half8*)&attF[af0 + o];
            if (myCnt > 1) {
                mn[1] = *(const half8*)&Mc[fb1 + o];
                an[1] = *(const half8*)&attF[af1 + o];
            }
        }
        half8 bfr[4];
        #pragma unroll
        for (int ft = 0; ft < 4; ++ft)
            bfr[ft] = *(const half8*)&xTs[(kt * 4 + ft) * 512 + lane * 8];

        dsum0 += hsum(mc[0]);
        if (myCnt > 1) dsum1 += hsum(mc[1]);

        #pragma unroll
        for (int vi = 0; vi < 2; ++vi) {
            if (vi < myCnt) {
                const half8 t  = mc[vi] * ac[vi];        // m*att
                const half8 a1 = -t;                     // -m*att
                const half8 a2 = (mc[vi] + mc[vi]) * t;  // 2m^2*att
                #pragma unroll
                for (int ft = 0; ft < 4; ++ft) {
                    acc1[vi][ft] = __builtin_amdgcn_mfma_f32_16x16x32_f16(a1, bfr[ft], acc1[vi][ft], 0, 0, 0);
                    acc2[vi][ft] = __builtin_amdgcn_mfma_f32_16x16x32_f16(a2, bfr[ft], acc2[vi][ft], 0, 0, 0);
                }
            }
        }
        #pragma unroll
        for (int vi = 0; vi < 2; ++vi) { mc[vi] = mn[vi]; ac[vi] = an[vi]; }
    }

    // d across q-groups; c = d - 1 - S_vv -> dbuf
    dsum0 += __shfl_xor(dsum0, 16); dsum0 += __shfl_xor(dsum0, 32);
    dsum1 += __shfl_xor(dsum1, 16); dsum1 += __shfl_xor(dsum1, 32);
    if (lane < 16) {
        const int vl0 = myBase * 16 + lane;
        dbuf[vl0] = dsum0 - 1.0f - sdb[vl0];
        if (myCnt > 1) {
            const int vl1 = (myBase + 1) * 16 + lane;
            dbuf[vl1] = dsum1 - 1.0f - sdb[vl1];
        }
    }

    // ---- epilogue: out-tiles += mfma(ys_k, ThT_k) for k = 1, 2, 0 (bf16) ----
    f32x4 ot[2][4];
    #pragma unroll
    for (int i = 0; i < 2; ++i)
        #pragma unroll
        for (int j = 0; j < 4; ++j) ot[i][j] = (f32x4)0.f;

    #pragma unroll
    for (int pass = 0; pass < 3; ++pass) {
        const int k = (pass == 0) ? 1 : (pass == 1) ? 2 : 0;
        __syncthreads();   // dbuf complete (pass 0); prev pass MFMA reads done

        if (k == 0) {
            for (int idx = tid; idx < 112 * 16; idx += 256) {
                const int vl = idx >> 4, fg = idx & 15;
                const int v = v0 + vl;
                u16x4 w; w[0] = 0; w[1] = 0; w[2] = 0; w[3] = 0;
                if (v < V) {
                    const float av = adb[vl];
                    const float4 xv = *(const float4*)&xp[v * F + 4 * fg];
                    w[0] = f2bf(av * xv.x); w[1] = f2bf(av * xv.y);
                    w[2] = f2bf(av * xv.z); w[3] = f2bf(av * xv.w);
                }
                *(u16x4*)&ys[vl * 72 + 4 * fg] = w;
            }
        } else {
            #pragma unroll
            for (int vi = 0; vi < 2; ++vi) {
                if (vi < myCnt) {
                    const int lt = myBase + vi;
                    #pragma unroll
                    for (int ft = 0; ft < 4; ++ft) {
                        const f32x4 a = (k == 1) ? acc1[vi][ft] : acc2[vi][ft];
                        #pragma unroll
                        for (int reg = 0; reg < 4; ++reg) {
                            const int vl = lt * 16 + 4 * q + reg;
                            const int v = v0 + vl;
                            float val = 0.f;
                            if (v < V) {
                                const float cc = dbuf[vl];
                                const float dc = ((k == 1) ? cc : (2.0f * cc * cc - 1.0f)) * adb[vl];
                                val = a[reg] + dc * xp[v * F + 16 * ft + ln];
                            }
                            ys[vl * 72 + 16 * ft + ln] = f2bf(val);
                        }
                    }
                }
            }
        }
        for (int idx = tid; idx < 512; idx += 256) {
            const int fo = idx >> 3, ch = idx & 7;
            *(u16x8*)&ThS[fo * 72 + 8 * ch] =
                *(const u16x8*)&thT[k * 4096 + fo * 64 + 8 * ch];
        }
        __syncthreads();
        #pragma unroll
        for (int vi = 0; vi < 2; ++vi) {
            if (vi < myCnt) {
                const int vrow = (myBase + vi) * 16 + ln;
                #pragma unroll
                for (int ks = 0; ks < 2; ++ks) {
                    const short8 af = *(const short8*)&ys[vrow * 72 + 32 * ks + 8 * q];
                    #pragma unroll
                    for (int fot = 0; fot < 4; ++fot) {
                        const short8 bf = *(const short8*)&ThS[(16 * fot + ln) * 72 + 32 * ks + 8 * q];
                        ot[vi][fot] = __builtin_amdgcn_mfma_f32_16x16x32_bf16(af, bf, ot[vi][fot], 0, 0, 0);
                    }
                }
            }
        }
    }

    // ---- relu + store ----
    #pragma unroll
    for (int vi = 0; vi < 2; ++vi) {
        if (vi < myCnt) {
            const int lt = myBase + vi;
            #pragma unroll
            for (int fot = 0; fot < 4; ++fot) {
                #pragma unroll
                for (int reg = 0; reg < 4; ++reg) {
                    const int v = v0 + lt * 16 + 4 * q + reg;
                    if (v < V)
                        op[v * F + 16 * fot + ln] = fmaxf(ot[vi][fot][reg], 0.f);
                }
            }
        }
    }
}

} // namespace

extern "C" void kernel_launch(void* const* d_in, const int* in_sizes, int n_in,
                              void* d_out, int out_size, void* d_ws, size_t ws_size,
                              hipStream_t stream) {
    const float* x     = (const float*)d_in[0];
    const float* Att   = (const float*)d_in[1];
    const float* S     = (const float*)d_in[2];
    const float* Theta = (const float*)d_in[3];
    float* out         = (float*)d_out;

    char* ws = (char*)d_ws;
    _Float16* Mc        = (_Float16*)(ws + WS_MC);
    _Float16* xTf       = (_Float16*)(ws + WS_XTF);
    _Float16* attF      = (_Float16*)(ws + WS_ATTF);
    unsigned short* thT = (unsigned short*)(ws + WS_THT);
    float* sdiag        = (float*)(ws + WS_SD);
    float* adiag        = (float*)(ws + WS_ADG);

    hipLaunchKernelGGL(prep_all, dim3(64, 29), dim3(256), 0, stream,
                       S, Att, x, Theta, Mc, attF, xTf, thT, sdiag, adiag);
    hipLaunchKernelGGL(cheb_stream, dim3(2 * NT), dim3(256), 0, stream,
                       x, Mc, attF, sdiag, adiag, thT, xTf, out);
}

// Round 9
// 213.496 us; speedup vs baseline: 1.2267x; 1.2267x over previous
//
#include <hip/hip_runtime.h>

namespace {

typedef __attribute__((ext_vector_type(8)))  short          short8;
typedef __attribute__((ext_vector_type(8)))  unsigned short u16x8;
typedef __attribute__((ext_vector_type(4)))  unsigned short u16x4;
typedef __attribute__((ext_vector_type(4)))  float          f32x4;
typedef __attribute__((ext_vector_type(8)))  _Float16       half8;
typedef __attribute__((ext_vector_type(4)))  _Float16       half4;
typedef __attribute__((ext_vector_type(2)))  _Float16       half2_t;

constexpr int V  = 200;
constexpr int F  = 64;
constexpr int NT = 512;   // N*T
constexpr int VP = 208;   // 13 x 16

// ---- ws layout (bytes) ----
// Mc  : f16 [512][13 tile][7 kt][64 lane][8]  = 47,710,208  (m = min(S,S^T), frag order)
// xTf : f16 [512][7 kt][4 ft][64 lane][8]     = 14,680,064  (x^T fragments)
// attF: f16 [8][13 tile][7 kt][64 lane][8]    =    745,472  (Att[u][v] fragments, 0 on diag)
// thT : ushort bf16 [3][64][64]               =     24,576
// sdg : f32 [512][208]  S[v][v]               =    425,984
// adg : f32 [8][208]    Att[v][v]             =      6,656
constexpr size_t WS_MC   = 0;
constexpr size_t WS_XTF  = 47710208;
constexpr size_t WS_ATTF = 62390272;
constexpr size_t WS_THT  = 63135744;
constexpr size_t WS_SD   = 63160320;
constexpr size_t WS_ADG  = 63586304;   // end 63,592,960

__device__ __forceinline__ unsigned short f2bf(float x) {
    union { float f; unsigned u; } c; c.f = x;
    unsigned r = c.u + 0x7FFF + ((c.u >> 16) & 1);
    return (unsigned short)(r >> 16);
}

// ============ P: merged prep, one-shot — grid (512, 29) ============
// y < 28 : tile-pair (ti<=tj) for batch b: S/Att tiles -> LDS (1 barrier) ->
//          Mc fragments both orientations (+attF when b%64==0; sdiag/adiag
//          on diag). No atomics, no d-sums (d computed in cheb_stream).
// y == 28: xTf fragments for batch b; b<3 additionally thT[k=b].
__global__ __launch_bounds__(256)
void prep_all(const float* __restrict__ S,
              const float* __restrict__ Att,
              const float* __restrict__ x,
              const float* __restrict__ Theta,
              _Float16* __restrict__ Mc,
              _Float16* __restrict__ attF,
              _Float16* __restrict__ xTf,
              unsigned short* __restrict__ thT,
              float* __restrict__ sdiag,
              float* __restrict__ adiag)
{
    __shared__ __align__(16) char smem[30464];
    const int b = blockIdx.x, n = b >> 6, tid = threadIdx.x;

    if (blockIdx.y == 28) {
        // ---- xTf path ----
        _Float16* xs = (_Float16*)smem;    // [224][68] f16
        const float* __restrict__ xp = x + (size_t)b * (V * F);
        for (int idx = tid; idx < 224 * 16; idx += 256) {
            const int u = idx >> 4, fg = idx & 15;
            half4 w = (half4)(_Float16)0.f;
            if (u < V) {
                const float4 v4 = *(const float4*)&xp[u * F + 4 * fg];
                w[0] = (_Float16)v4.x; w[1] = (_Float16)v4.y;
                w[2] = (_Float16)v4.z; w[3] = (_Float16)v4.w;
            }
            *(half4*)&xs[u * 68 + 4 * fg] = w;
        }
        __syncthreads();
        // frag = kt*4+ft; lane holds x[u=32kt+8q+j][f=16ft+ln]
        _Float16* xo = xTf + (size_t)b * 14336;
        for (int it = 0; it < 7; ++it) {
            const int wid = tid + 256 * it;            // 0..1791
            const int frag = wid >> 6, lane = wid & 63;
            const int kt = frag >> 2, ft = frag & 3;
            const int q = lane >> 4, ln = lane & 15;
            half8 w;
            #pragma unroll
            for (int j = 0; j < 8; ++j)
                w[j] = xs[(32 * kt + 8 * q + j) * 68 + 16 * ft + ln];
            *(half8*)&xo[frag * 512 + lane * 8] = w;
        }
        if (b < 3) {
            const int k = b;
            __syncthreads();                           // xs reads done
            float* T = (float*)smem;                   // [64][65] f32
            for (int idx = tid; idx < 4096; idx += 256)
                T[(idx >> 6) * 65 + (idx & 63)] = Theta[k * 4096 + idx];
            __syncthreads();
            for (int idx = tid; idx < 4096; idx += 256) {
                const int fo = idx >> 6, f = idx & 63;
                thT[k * 4096 + fo * 64 + f] = f2bf(T[f * 65 + fo]);
            }
        }
        return;
    }

    // ---- tile-pair path (one-shot; R7 lineage minus d/Ms/atomics) ----
    float (*As)[33] = (float(*)[33])smem;                 // S  [ti-rows][tj-cols]
    float (*Bs)[33] = (float(*)[33])(smem + 4224);        // S  [tj-rows][ti-cols]
    float (*Ts)[33] = (float(*)[33])(smem + 8448);        // Att[ti-rows][tj-cols]
    float (*Us)[33] = (float(*)[33])(smem + 12672);       // Att[tj-rows][ti-cols] (ends 16,896)

    int rem = blockIdx.y, ti = 0;
    while (rem >= 7 - ti) { rem -= 7 - ti; ++ti; }
    const int tj = ti + rem;
    const bool diag = (ti == tj);

    const float* __restrict__ Sp = S   + (size_t)b * (V * V);
    const float* __restrict__ Ap = Att + (size_t)n * (V * V);

    const int r = tid >> 3, cg = tid & 7, c0 = 4 * cg;

    {
        const int gr = 32 * ti + r, gc = 32 * tj + c0;
        float4 a = make_float4(0.f, 0.f, 0.f, 0.f);
        float4 t = make_float4(0.f, 0.f, 0.f, 0.f);
        if (gr < V && gc < V) {
            a = *(const float4*)&Sp[gr * V + gc];
            t = *(const float4*)&Ap[gr * V + gc];
        }
        As[r][c0+0] = a.x; As[r][c0+1] = a.y; As[r][c0+2] = a.z; As[r][c0+3] = a.w;
        Ts[r][c0+0] = t.x; Ts[r][c0+1] = t.y; Ts[r][c0+2] = t.z; Ts[r][c0+3] = t.w;
        if (!diag) {
            const int hr = 32 * tj + r, hc = 32 * ti + c0;
            float4 bb = make_float4(0.f, 0.f, 0.f, 0.f);
            float4 uu = make_float4(0.f, 0.f, 0.f, 0.f);
            if (hr < V && hc < V) {
                bb = *(const float4*)&Sp[hr * V + hc];
                uu = *(const float4*)&Ap[hr * V + hc];
            }
            Bs[r][c0+0] = bb.x; Bs[r][c0+1] = bb.y; Bs[r][c0+2] = bb.z; Bs[r][c0+3] = bb.w;
            Us[r][c0+0] = uu.x; Us[r][c0+1] = uu.y; Us[r][c0+2] = uu.z; Us[r][c0+3] = uu.w;
        }
    }
    __syncthreads();   // the only barrier

    // diag scalar files (32 threads)
    if (diag && cg == 0) {
        const int vg = 32 * ti + r;
        if (vg < VP) {
            sdiag[b * VP + vg] = As[r][r];             // 0 for padded rows
            if ((b & 63) == 0) adiag[n * VP + vg] = Ts[r][r];
        }
    }

    // ---- fragment writes (min computed inline; R8-verified math) ----
    const int jh = tid & 1, lane = (tid >> 1) & 63, sub = tid >> 7;
    const int rr = lane & 15, qq = lane >> 4;
    const int vl = sub * 16 + rr;          // 0..31 within the 32-row block
    const int ub2 = 8 * qq + 4 * jh;       // u_local base
    const bool wAtt = ((b & 63) == 0);

    // orientation 1: v in ti-block (tiles 2ti+sub), kt = tj
    if (2 * ti + sub < 13) {
        half4 wm, wa;
        #pragma unroll
        for (int e = 0; e < 4; ++e) {
            const int ul = ub2 + e;
            const float mB = diag ? As[ul][vl] : Bs[ul][vl];
            wm[e] = (_Float16)fminf(As[vl][ul], mB);
            const float att = diag ? Ts[ul][vl] : Us[ul][vl];   // Att[u][v]
            wa[e] = (diag && ul == vl) ? (_Float16)0.f : (_Float16)att;
        }
        const size_t base = ((size_t)(b * 13 + 2 * ti + sub) * 7 + tj) * 512 + lane * 8 + jh * 4;
        *(half4*)&Mc[base] = wm;
        if (wAtt) {
            const size_t ab = ((size_t)(n * 13 + 2 * ti + sub) * 7 + tj) * 512 + lane * 8 + jh * 4;
            *(half4*)&attF[ab] = wa;
        }
    }
    // mirror: v in tj-block (tiles 2tj+sub), kt = ti
    if (!diag && 2 * tj + sub < 13) {
        half4 wm, wa;
        #pragma unroll
        for (int e = 0; e < 4; ++e) {
            const int ul = ub2 + e;
            wm[e] = (_Float16)fminf(Bs[vl][ul], As[ul][vl]);   // min(S[v'][u'],S[u'][v'])
            wa[e] = (_Float16)Ts[ul][vl];                      // Att[u'][v'], u'!=v'
        }
        const size_t base = ((size_t)(b * 13 + 2 * tj + sub) * 7 + ti) * 512 + lane * 8 + jh * 4;
        *(half4*)&Mc[base] = wm;
        if (wAtt) {
            const size_t ab = ((size_t)(n * 13 + 2 * tj + sub) * 7 + ti) * 512 + lane * 8 + jh * 4;
            *(half4*)&attF[ab] = wa;
        }
    }
}

// ============ G: streaming MFMA kernel — d computed on the fly ============
// (byte-identical to R8's cheb_stream)
__global__ __launch_bounds__(256, 4)
void cheb_stream(const float* __restrict__ x,
                 const _Float16* __restrict__ Mc,
                 const _Float16* __restrict__ attF,
                 const float* __restrict__ sdiag,
                 const float* __restrict__ adiag,
                 const unsigned short* __restrict__ thT,
                 const _Float16* __restrict__ xTf,
                 float* __restrict__ out)
{
    __shared__ __align__(16) char smem[30080];
    _Float16*       xTs = (_Float16*)smem;                  // 28,672 B (K loop)
    unsigned short* ys  = (unsigned short*)smem;            // [112][72] = 16,128 (epi)
    unsigned short* ThS = (unsigned short*)(smem + 16128);  // [64][72]  =  9,216 (epi)
    float* dbuf = (float*)(smem + 28672);                   // [112] c = d-1-S_vv
    float* adb  = (float*)(smem + 29120);                   // [112] Att[v][v]
    float* sdb  = (float*)(smem + 29568);                   // [112] S[v][v]

    const int tid = threadIdx.x;
    const int ub_ = blockIdx.x;
    const int h   = (ub_ >> 3) & 1;
    const int b   = (ub_ & 7) | ((ub_ >> 4) << 3);
    const int n   = b >> 6;
    const int v0  = h * 112;

    // stage xTf -> LDS (coalesced, once)
    const _Float16* __restrict__ xfp = xTf + (size_t)b * 14336;
    #pragma unroll
    for (int it = 0; it < 7; ++it) {
        const int o = it * 2048 + tid * 8;
        *(half8*)&xTs[o] = *(const half8*)&xfp[o];
    }
    if (tid < 112) {
        const int gv = v0 + tid;
        adb[tid] = (gv < VP) ? adiag[n * VP + gv] : 0.f;
        sdb[tid] = (gv < VP) ? sdiag[b * VP + gv] : 0.f;
    }

    const int wave = tid >> 6, lane = tid & 63, q = lane >> 4, ln = lane & 15;
    int myBase, myCnt;
    if (h == 0) { myCnt = (wave < 3) ? 2 : 1; myBase = 2 * wave; }
    else        { myCnt = (wave < 2) ? 2 : 1; myBase = (wave < 2) ? 2 * wave : 2 + wave; }

    const float* __restrict__ xp = x + (size_t)b * (V * F);
    float* __restrict__ op = out + (size_t)b * (V * F);

    f32x4 acc1[2][4], acc2[2][4];
    #pragma unroll
    for (int i = 0; i < 2; ++i)
        #pragma unroll
        for (int j = 0; j < 4; ++j) { acc1[i][j] = (f32x4)0.f; acc2[i][j] = (f32x4)0.f; }

    // fragment bases (f16 element index at kt=0); tiles are 7*512 apart
    const size_t fb0 = ((size_t)(b * 13 + 7 * h + myBase) * 7) * 512 + lane * 8;
    const size_t fb1 = fb0 + 7 * 512;
    const size_t af0 = ((size_t)(n * 13 + 7 * h + myBase) * 7) * 512 + lane * 8;
    const size_t af1 = af0 + 7 * 512;

    half8 mc[2] = {}, ac[2] = {}, mn[2] = {}, an[2] = {};
    mc[0] = *(const half8*)&Mc[fb0];
    ac[0] = *(const half8*)&attF[af0];
    if (myCnt > 1) {
        mc[1] = *(const half8*)&Mc[fb1];
        ac[1] = *(const half8*)&attF[af1];
    }
    __syncthreads();   // xTs/adb/sdb ready

    float dsum0 = 0.f, dsum1 = 0.f;
    auto hsum = [](half8 m) -> float {
        const half2_t a = __builtin_shufflevector(m, m, 0, 1) + __builtin_shufflevector(m, m, 2, 3);
        const half2_t c = __builtin_shufflevector(m, m, 4, 5) + __builtin_shufflevector(m, m, 6, 7);
        const half2_t s = a + c;
        return (float)s[0] + (float)s[1];
    };

    #pragma unroll 1
    for (int kt = 0; kt < 7; ++kt) {
        if (kt < 6) {
            const size_t o = (size_t)(kt + 1) * 512;
            mn[0] = *(const half8*)&Mc[fb0 + o];
            an[0] = *(const half8*)&attF[af0 + o];
            if (myCnt > 1) {
                mn[1] = *(const half8*)&Mc[fb1 + o];
                an[1] = *(const half8*)&attF[af1 + o];
            }
        }
        half8 bfr[4];
        #pragma unroll
        for (int ft = 0; ft < 4; ++ft)
            bfr[ft] = *(const half8*)&xTs[(kt * 4 + ft) * 512 + lane * 8];

        dsum0 += hsum(mc[0]);
        if (myCnt > 1) dsum1 += hsum(mc[1]);

        #pragma unroll
        for (int vi = 0; vi < 2; ++vi) {
            if (vi < myCnt) {
                const half8 t  = mc[vi] * ac[vi];        // m*att
                const half8 a1 = -t;                     // -m*att
                const half8 a2 = (mc[vi] + mc[vi]) * t;  // 2m^2*att
                #pragma unroll
                for (int ft = 0; ft < 4; ++ft) {
                    acc1[vi][ft] = __builtin_amdgcn_mfma_f32_16x16x32_f16(a1, bfr[ft], acc1[vi][ft], 0, 0, 0);
                    acc2[vi][ft] = __builtin_amdgcn_mfma_f32_16x16x32_f16(a2, bfr[ft], acc2[vi][ft], 0, 0, 0);
                }
            }
        }
        #pragma unroll
        for (int vi = 0; vi < 2; ++vi) { mc[vi] = mn[vi]; ac[vi] = an[vi]; }
    }

    // d across q-groups; c = d - 1 - S_vv -> dbuf
    dsum0 += __shfl_xor(dsum0, 16); dsum0 += __shfl_xor(dsum0, 32);
    dsum1 += __shfl_xor(dsum1, 16); dsum1 += __shfl_xor(dsum1, 32);
    if (lane < 16) {
        const int vl0 = myBase * 16 + lane;
        dbuf[vl0] = dsum0 - 1.0f - sdb[vl0];
        if (myCnt > 1) {
            const int vl1 = (myBase + 1) * 16 + lane;
            dbuf[vl1] = dsum1 - 1.0f - sdb[vl1];
        }
    }

    // ---- epilogue: out-tiles += mfma(ys_k, ThT_k) for k = 1, 2, 0 (bf16) ----
    f32x4 ot[2][4];
    #pragma unroll
    for (int i = 0; i < 2; ++i)
        #pragma unroll
        for (int j = 0; j < 4; ++j) ot[i][j] = (f32x4)0.f;

    #pragma unroll
    for (int pass = 0; pass < 3; ++pass) {
        const int k = (pass == 0) ? 1 : (pass == 1) ? 2 : 0;
        __syncthreads();   // dbuf complete (pass 0); prev pass MFMA reads done

        if (k == 0) {
            for (int idx = tid; idx < 112 * 16; idx += 256) {
                const int vl = idx >> 4, fg = idx & 15;
                const int v = v0 + vl;
                u16x4 w; w[0] = 0; w[1] = 0; w[2] = 0; w[3] = 0;
                if (v < V) {
                    const float av = adb[vl];
                    const float4 xv = *(const float4*)&xp[v * F + 4 * fg];
                    w[0] = f2bf(av * xv.x); w[1] = f2bf(av * xv.y);
                    w[2] = f2bf(av * xv.z); w[3] = f2bf(av * xv.w);
                }
                *(u16x4*)&ys[vl * 72 + 4 * fg] = w;
            }
        } else {
            #pragma unroll
            for (int vi = 0; vi < 2; ++vi) {
                if (vi < myCnt) {
                    const int lt = myBase + vi;
                    #pragma unroll
                    for (int ft = 0; ft < 4; ++ft) {
                        const f32x4 a = (k == 1) ? acc1[vi][ft] : acc2[vi][ft];
                        #pragma unroll
                        for (int reg = 0; reg < 4; ++reg) {
                            const int vl = lt * 16 + 4 * q + reg;
                            const int v = v0 + vl;
                            float val = 0.f;
                            if (v < V) {
                                const float cc = dbuf[vl];
                                const float dc = ((k == 1) ? cc : (2.0f * cc * cc - 1.0f)) * adb[vl];
                                val = a[reg] + dc * xp[v * F + 16 * ft + ln];
                            }
                            ys[vl * 72 + 16 * ft + ln] = f2bf(val);
                        }
                    }
                }
            }
        }
        for (int idx = tid; idx < 512; idx += 256) {
            const int fo = idx >> 3, ch = idx & 7;
            *(u16x8*)&ThS[fo * 72 + 8 * ch] =
                *(const u16x8*)&thT[k * 4096 + fo * 64 + 8 * ch];
        }
        __syncthreads();
        #pragma unroll
        for (int vi = 0; vi < 2; ++vi) {
            if (vi < myCnt) {
                const int vrow = (myBase + vi) * 16 + ln;
                #pragma unroll
                for (int ks = 0; ks < 2; ++ks) {
                    const short8 af = *(const short8*)&ys[vrow * 72 + 32 * ks + 8 * q];
                    #pragma unroll
                    for (int fot = 0; fot < 4; ++fot) {
                        const short8 bf = *(const short8*)&ThS[(16 * fot + ln) * 72 + 32 * ks + 8 * q];
                        ot[vi][fot] = __builtin_amdgcn_mfma_f32_16x16x32_bf16(af, bf, ot[vi][fot], 0, 0, 0);
                    }
                }
            }
        }
    }

    // ---- relu + store ----
    #pragma unroll
    for (int vi = 0; vi < 2; ++vi) {
        if (vi < myCnt) {
            const int lt = myBase + vi;
            #pragma unroll
            for (int fot = 0; fot < 4; ++fot) {
                #pragma unroll
                for (int reg = 0; reg < 4; ++reg) {
                    const int v = v0 + lt * 16 + 4 * q + reg;
                    if (v < V)
                        op[v * F + 16 * fot + ln] = fmaxf(ot[vi][fot][reg], 0.f);
                }
            }
        }
    }
}

} // namespace

extern "C" void kernel_launch(void* const* d_in, const int* in_sizes, int n_in,
                              void* d_out, int out_size, void* d_ws, size_t ws_size,
                              hipStream_t stream) {
    const float* x     = (const float*)d_in[0];
    const float* Att   = (const float*)d_in[1];
    const float* S     = (const float*)d_in[2];
    const float* Theta = (const float*)d_in[3];
    float* out         = (float*)d_out;

    char* ws = (char*)d_ws;
    _Float16* Mc        = (_Float16*)(ws + WS_MC);
    _Float16* xTf       = (_Float16*)(ws + WS_XTF);
    _Float16* attF      = (_Float16*)(ws + WS_ATTF);
    unsigned short* thT = (unsigned short*)(ws + WS_THT);
    float* sdiag        = (float*)(ws + WS_SD);
    float* adiag        = (float*)(ws + WS_ADG);

    hipLaunchKernelGGL(prep_all, dim3(NT, 29), dim3(256), 0, stream,
                       S, Att, x, Theta, Mc, attF, xTf, thT, sdiag, adiag);
    hipLaunchKernelGGL(cheb_stream, dim3(2 * NT), dim3(256), 0, stream,
                       x, Mc, attF, sdiag, adiag, thT, xTf, out);
}

// Round 11
// 205.593 us; speedup vs baseline: 1.2739x; 1.0384x over previous
//
#include <hip/hip_runtime.h>

namespace {

typedef __attribute__((ext_vector_type(8)))  short          short8;
typedef __attribute__((ext_vector_type(8)))  unsigned short u16x8;
typedef __attribute__((ext_vector_type(4)))  unsigned short u16x4;
typedef __attribute__((ext_vector_type(4)))  float          f32x4;
typedef __attribute__((ext_vector_type(8)))  _Float16       half8;
typedef __attribute__((ext_vector_type(4)))  _Float16       half4;
typedef __attribute__((ext_vector_type(2)))  _Float16       half2_t;

constexpr int V  = 200;
constexpr int F  = 64;
constexpr int NT = 512;   // N*T
constexpr int VP = 208;   // 13 x 16

// ---- ws layout (bytes) ----
// Mc  : f16 [512][13 tile][7 kt][64 lane][8]  = 47,710,208  (m = min(S,S^T), frag order)
// xTf : f16 [512][7 kt][4 ft][64 lane][8]     = 14,680,064  (x^T fragments)
// attF: f16 [8][13 tile][7 kt][64 lane][8]    =    745,472  (Att[u][v] fragments, 0 on diag)
// thT : ushort bf16 [3][64][64]               =     24,576
// sdg : f32 [512][208]  S[v][v]               =    425,984
// adg : f32 [8][208]    Att[v][v]             =      6,656
constexpr size_t WS_MC   = 0;
constexpr size_t WS_XTF  = 47710208;
constexpr size_t WS_ATTF = 62390272;
constexpr size_t WS_THT  = 63135744;
constexpr size_t WS_SD   = 63160320;
constexpr size_t WS_ADG  = 63586304;   // end 63,592,960

__device__ __forceinline__ unsigned short f2bf(float x) {
    union { float f; unsigned u; } c; c.f = x;
    unsigned r = c.u + 0x7FFF + ((c.u >> 16) & 1);
    return (unsigned short)(r >> 16);
}

// ============ P: merged prep, b-paired — grid (256, 30) ============
// y < 28 : tile-pair (ti<=tj) for batches b0=2bx, b1=2bx+1 (same n):
//          4 S tiles + 2 shared Att tiles -> LDS (6 independent loads, 96B/thread
//          in flight, 1 barrier) -> Mc fragments both orientations, both b's
//          (+attF when b0%64==0; sdiag both b's / adiag on diag).
// y == 28: xTf fragments for b0 (bx<3: thT[k=bx]).   y == 29: xTf for b1.
__global__ __launch_bounds__(256)
void prep_all(const float* __restrict__ S,
              const float* __restrict__ Att,
              const float* __restrict__ x,
              const float* __restrict__ Theta,
              _Float16* __restrict__ Mc,
              _Float16* __restrict__ attF,
              _Float16* __restrict__ xTf,
              unsigned short* __restrict__ thT,
              float* __restrict__ sdiag,
              float* __restrict__ adiag)
{
    __shared__ __align__(16) char smem[30464];
    const int bx = blockIdx.x, tid = threadIdx.x;

    if (blockIdx.y >= 28) {
        // ---- xTf path: one b per block ----
        const int b = 2 * bx + (blockIdx.y - 28);
        _Float16* xs = (_Float16*)smem;    // [224][68] f16
        const float* __restrict__ xp = x + (size_t)b * (V * F);
        for (int idx = tid; idx < 224 * 16; idx += 256) {
            const int u = idx >> 4, fg = idx & 15;
            half4 w = (half4)(_Float16)0.f;
            if (u < V) {
                const float4 v4 = *(const float4*)&xp[u * F + 4 * fg];
                w[0] = (_Float16)v4.x; w[1] = (_Float16)v4.y;
                w[2] = (_Float16)v4.z; w[3] = (_Float16)v4.w;
            }
            *(half4*)&xs[u * 68 + 4 * fg] = w;
        }
        __syncthreads();
        // frag = kt*4+ft; lane holds x[u=32kt+8q+j][f=16ft+ln]
        _Float16* xo = xTf + (size_t)b * 14336;
        for (int it = 0; it < 7; ++it) {
            const int wid = tid + 256 * it;            // 0..1791
            const int frag = wid >> 6, lane = wid & 63;
            const int kt = frag >> 2, ft = frag & 3;
            const int q = lane >> 4, ln = lane & 15;
            half8 w;
            #pragma unroll
            for (int j = 0; j < 8; ++j)
                w[j] = xs[(32 * kt + 8 * q + j) * 68 + 16 * ft + ln];
            *(half8*)&xo[frag * 512 + lane * 8] = w;
        }
        if (blockIdx.y == 28 && bx < 3) {
            const int k = bx;
            __syncthreads();                           // xs reads done
            float* T = (float*)smem;                   // [64][65] f32
            for (int idx = tid; idx < 4096; idx += 256)
                T[(idx >> 6) * 65 + (idx & 63)] = Theta[k * 4096 + idx];
            __syncthreads();
            for (int idx = tid; idx < 4096; idx += 256) {
                const int fo = idx >> 6, f = idx & 63;
                thT[k * 4096 + fo * 64 + f] = f2bf(T[f * 65 + fo]);
            }
        }
        return;
    }

    // ---- tile-pair path, two b's ----
    float (*As0)[33] = (float(*)[33])smem;                 // S[b0] [ti-rows][tj-cols]
    float (*Bs0)[33] = (float(*)[33])(smem + 4224);        // S[b0] [tj-rows][ti-cols]
    float (*As1)[33] = (float(*)[33])(smem + 8448);        // S[b1]
    float (*Bs1)[33] = (float(*)[33])(smem + 12672);       // S[b1]
    float (*Ts)[33]  = (float(*)[33])(smem + 16896);       // Att [ti-rows][tj-cols]
    float (*Us)[33]  = (float(*)[33])(smem + 21120);       // Att [tj-rows][ti-cols] (ends 25,344)

    int rem = blockIdx.y, ti = 0;
    while (rem >= 7 - ti) { rem -= 7 - ti; ++ti; }
    const int tj = ti + rem;
    const bool diag = (ti == tj);

    const int b0 = 2 * bx, n = b0 >> 6;
    const float* __restrict__ Sp0 = S   + (size_t)b0 * (V * V);
    const float* __restrict__ Sp1 = Sp0 + (V * V);
    const float* __restrict__ Ap  = Att + (size_t)n * (V * V);

    const int r = tid >> 3, cg = tid & 7, c0 = 4 * cg;

    {
        const int gr = 32 * ti + r, gc = 32 * tj + c0;
        const bool ok1 = (gr < V && gc < V);
        float4 a0 = make_float4(0.f,0.f,0.f,0.f), a1 = make_float4(0.f,0.f,0.f,0.f);
        float4 t  = make_float4(0.f,0.f,0.f,0.f);
        if (ok1) {
            a0 = *(const float4*)&Sp0[gr * V + gc];
            a1 = *(const float4*)&Sp1[gr * V + gc];
            t  = *(const float4*)&Ap [gr * V + gc];
        }
        As0[r][c0+0]=a0.x; As0[r][c0+1]=a0.y; As0[r][c0+2]=a0.z; As0[r][c0+3]=a0.w;
        As1[r][c0+0]=a1.x; As1[r][c0+1]=a1.y; As1[r][c0+2]=a1.z; As1[r][c0+3]=a1.w;
        Ts [r][c0+0]=t.x;  Ts [r][c0+1]=t.y;  Ts [r][c0+2]=t.z;  Ts [r][c0+3]=t.w;
        if (!diag) {
            const int hr = 32 * tj + r, hc = 32 * ti + c0;
            const bool ok2 = (hr < V && hc < V);
            float4 b0t = make_float4(0.f,0.f,0.f,0.f), b1t = make_float4(0.f,0.f,0.f,0.f);
            float4 u   = make_float4(0.f,0.f,0.f,0.f);
            if (ok2) {
                b0t = *(const float4*)&Sp0[hr * V + hc];
                b1t = *(const float4*)&Sp1[hr * V + hc];
                u   = *(const float4*)&Ap [hr * V + hc];
            }
            Bs0[r][c0+0]=b0t.x; Bs0[r][c0+1]=b0t.y; Bs0[r][c0+2]=b0t.z; Bs0[r][c0+3]=b0t.w;
            Bs1[r][c0+0]=b1t.x; Bs1[r][c0+1]=b1t.y; Bs1[r][c0+2]=b1t.z; Bs1[r][c0+3]=b1t.w;
            Us [r][c0+0]=u.x;   Us [r][c0+1]=u.y;   Us [r][c0+2]=u.z;   Us [r][c0+3]=u.w;
        }
    }
    __syncthreads();   // the only barrier

    // diag scalar files (32 threads)
    if (diag && cg == 0) {
        const int vg = 32 * ti + r;
        if (vg < VP) {
            sdiag[(size_t)b0 * VP + vg]       = As0[r][r];   // 0 for padded rows
            sdiag[(size_t)(b0 + 1) * VP + vg] = As1[r][r];
            if ((b0 & 63) == 0) adiag[n * VP + vg] = Ts[r][r];
        }
    }

    // ---- fragment writes (R8-verified math, both b's) ----
    const int jh = tid & 1, lane = (tid >> 1) & 63, sub = tid >> 7;
    const int rr = lane & 15, qq = lane >> 4;
    const int vl = sub * 16 + rr;          // 0..31 within the 32-row block
    const int ub2 = 8 * qq + 4 * jh;       // u_local base
    const bool wAtt = ((b0 & 63) == 0);    // only b0 can qualify

    #pragma unroll
    for (int bb = 0; bb < 2; ++bb) {
        float (*As)[33] = bb ? As1 : As0;
        float (*Bs)[33] = bb ? Bs1 : Bs0;
        const int b = b0 + bb;

        // orientation 1: v in ti-block (tiles 2ti+sub), kt = tj
        if (2 * ti + sub < 13) {
            half4 wm, wa;
            #pragma unroll
            for (int e = 0; e < 4; ++e) {
                const int ul = ub2 + e;
                const float mB = diag ? As[ul][vl] : Bs[ul][vl];
                wm[e] = (_Float16)fminf(As[vl][ul], mB);
                const float att = diag ? Ts[ul][vl] : Us[ul][vl];   // Att[u][v]
                wa[e] = (diag && ul == vl) ? (_Float16)0.f : (_Float16)att;
            }
            const size_t base = ((size_t)(b * 13 + 2 * ti + sub) * 7 + tj) * 512 + lane * 8 + jh * 4;
            *(half4*)&Mc[base] = wm;
            if (wAtt && bb == 0) {
                const size_t ab = ((size_t)(n * 13 + 2 * ti + sub) * 7 + tj) * 512 + lane * 8 + jh * 4;
                *(half4*)&attF[ab] = wa;
            }
        }
        // mirror: v in tj-block (tiles 2tj+sub), kt = ti
        if (!diag && 2 * tj + sub < 13) {
            half4 wm, wa;
            #pragma unroll
            for (int e = 0; e < 4; ++e) {
                const int ul = ub2 + e;
                wm[e] = (_Float16)fminf(Bs[vl][ul], As[ul][vl]);   // min(S[v'][u'],S[u'][v'])
                wa[e] = (_Float16)Ts[ul][vl];                      // Att[u'][v'], u'!=v'
            }
            const size_t base = ((size_t)(b * 13 + 2 * tj + sub) * 7 + ti) * 512 + lane * 8 + jh * 4;
            *(half4*)&Mc[base] = wm;
            if (wAtt && bb == 0) {
                const size_t ab = ((size_t)(n * 13 + 2 * tj + sub) * 7 + ti) * 512 + lane * 8 + jh * 4;
                *(half4*)&attF[ab] = wa;
            }
        }
    }
}

// ============ G: streaming MFMA kernel — d computed on the fly ============
// (byte-identical to R9's cheb_stream)
__global__ __launch_bounds__(256, 4)
void cheb_stream(const float* __restrict__ x,
                 const _Float16* __restrict__ Mc,
                 const _Float16* __restrict__ attF,
                 const float* __restrict__ sdiag,
                 const float* __restrict__ adiag,
                 const unsigned short* __restrict__ thT,
                 const _Float16* __restrict__ xTf,
                 float* __restrict__ out)
{
    __shared__ __align__(16) char smem[30080];
    _Float16*       xTs = (_Float16*)smem;                  // 28,672 B (K loop)
    unsigned short* ys  = (unsigned short*)smem;            // [112][72] = 16,128 (epi)
    unsigned short* ThS = (unsigned short*)(smem + 16128);  // [64][72]  =  9,216 (epi)
    float* dbuf = (float*)(smem + 28672);                   // [112] c = d-1-S_vv
    float* adb  = (float*)(smem + 29120);                   // [112] Att[v][v]
    float* sdb  = (float*)(smem + 29568);                   // [112] S[v][v]

    const int tid = threadIdx.x;
    const int ub_ = blockIdx.x;
    const int h   = (ub_ >> 3) & 1;
    const int b   = (ub_ & 7) | ((ub_ >> 4) << 3);
    const int n   = b >> 6;
    const int v0  = h * 112;

    // stage xTf -> LDS (coalesced, once)
    const _Float16* __restrict__ xfp = xTf + (size_t)b * 14336;
    #pragma unroll
    for (int it = 0; it < 7; ++it) {
        const int o = it * 2048 + tid * 8;
        *(half8*)&xTs[o] = *(const half8*)&xfp[o];
    }
    if (tid < 112) {
        const int gv = v0 + tid;
        adb[tid] = (gv < VP) ? adiag[n * VP + gv] : 0.f;
        sdb[tid] = (gv < VP) ? sdiag[b * VP + gv] : 0.f;
    }

    const int wave = tid >> 6, lane = tid & 63, q = lane >> 4, ln = lane & 15;
    int myBase, myCnt;
    if (h == 0) { myCnt = (wave < 3) ? 2 : 1; myBase = 2 * wave; }
    else        { myCnt = (wave < 2) ? 2 : 1; myBase = (wave < 2) ? 2 * wave : 2 + wave; }

    const float* __restrict__ xp = x + (size_t)b * (V * F);
    float* __restrict__ op = out + (size_t)b * (V * F);

    f32x4 acc1[2][4], acc2[2][4];
    #pragma unroll
    for (int i = 0; i < 2; ++i)
        #pragma unroll
        for (int j = 0; j < 4; ++j) { acc1[i][j] = (f32x4)0.f; acc2[i][j] = (f32x4)0.f; }

    // fragment bases (f16 element index at kt=0); tiles are 7*512 apart
    const size_t fb0 = ((size_t)(b * 13 + 7 * h + myBase) * 7) * 512 + lane * 8;
    const size_t fb1 = fb0 + 7 * 512;
    const size_t af0 = ((size_t)(n * 13 + 7 * h + myBase) * 7) * 512 + lane * 8;
    const size_t af1 = af0 + 7 * 512;

    half8 mc[2] = {}, ac[2] = {}, mn[2] = {}, an[2] = {};
    mc[0] = *(const half8*)&Mc[fb0];
    ac[0] = *(const half8*)&attF[af0];
    if (myCnt > 1) {
        mc[1] = *(const half8*)&Mc[fb1];
        ac[1] = *(const half8*)&attF[af1];
    }
    __syncthreads();   // xTs/adb/sdb ready

    float dsum0 = 0.f, dsum1 = 0.f;
    auto hsum = [](half8 m) -> float {
        const half2_t a = __builtin_shufflevector(m, m, 0, 1) + __builtin_shufflevector(m, m, 2, 3);
        const half2_t c = __builtin_shufflevector(m, m, 4, 5) + __builtin_shufflevector(m, m, 6, 7);
        const half2_t s = a + c;
        return (float)s[0] + (float)s[1];
    };

    #pragma unroll 1
    for (int kt = 0; kt < 7; ++kt) {
        if (kt < 6) {
            const size_t o = (size_t)(kt + 1) * 512;
            mn[0] = *(const half8*)&Mc[fb0 + o];
            an[0] = *(const half8*)&attF[af0 + o];
            if (myCnt > 1) {
                mn[1] = *(const half8*)&Mc[fb1 + o];
                an[1] = *(const half8*)&attF[af1 + o];
            }
        }
        half8 bfr[4];
        #pragma unroll
        for (int ft = 0; ft < 4; ++ft)
            bfr[ft] = *(const half8*)&xTs[(kt * 4 + ft) * 512 + lane * 8];

        dsum0 += hsum(mc[0]);
        if (myCnt > 1) dsum1 += hsum(mc[1]);

        #pragma unroll
        for (int vi = 0; vi < 2; ++vi) {
            if (vi < myCnt) {
                const half8 t  = mc[vi] * ac[vi];        // m*att
                const half8 a1 = -t;                     // -m*att
                const half8 a2 = (mc[vi] + mc[vi]) * t;  // 2m^2*att
                #pragma unroll
                for (int ft = 0; ft < 4; ++ft) {
                    acc1[vi][ft] = __builtin_amdgcn_mfma_f32_16x16x32_f16(a1, bfr[ft], acc1[vi][ft], 0, 0, 0);
                    acc2[vi][ft] = __builtin_amdgcn_mfma_f32_16x16x32_f16(a2, bfr[ft], acc2[vi][ft], 0, 0, 0);
                }
            }
        }
        #pragma unroll
        for (int vi = 0; vi < 2; ++vi) { mc[vi] = mn[vi]; ac[vi] = an[vi]; }
    }

    // d across q-groups; c = d - 1 - S_vv -> dbuf
    dsum0 += __shfl_xor(dsum0, 16); dsum0 += __shfl_xor(dsum0, 32);
    dsum1 += __shfl_xor(dsum1, 16); dsum1 += __shfl_xor(dsum1, 32);
    if (lane < 16) {
        const int vl0 = myBase * 16 + lane;
        dbuf[vl0] = dsum0 - 1.0f - sdb[vl0];
        if (myCnt > 1) {
            const int vl1 = (myBase + 1) * 16 + lane;
            dbuf[vl1] = dsum1 - 1.0f - sdb[vl1];
        }
    }

    // ---- epilogue: out-tiles += mfma(ys_k, ThT_k) for k = 1, 2, 0 (bf16) ----
    f32x4 ot[2][4];
    #pragma unroll
    for (int i = 0; i < 2; ++i)
        #pragma unroll
        for (int j = 0; j < 4; ++j) ot[i][j] = (f32x4)0.f;

    #pragma unroll
    for (int pass = 0; pass < 3; ++pass) {
        const int k = (pass == 0) ? 1 : (pass == 1) ? 2 : 0;
        __syncthreads();   // dbuf complete (pass 0); prev pass MFMA reads done

        if (k == 0) {
            for (int idx = tid; idx < 112 * 16; idx += 256) {
                const int vl = idx >> 4, fg = idx & 15;
                const int v = v0 + vl;
                u16x4 w; w[0] = 0; w[1] = 0; w[2] = 0; w[3] = 0;
                if (v < V) {
                    const float av = adb[vl];
                    const float4 xv = *(const float4*)&xp[v * F + 4 * fg];
                    w[0] = f2bf(av * xv.x); w[1] = f2bf(av * xv.y);
                    w[2] = f2bf(av * xv.z); w[3] = f2bf(av * xv.w);
                }
                *(u16x4*)&ys[vl * 72 + 4 * fg] = w;
            }
        } else {
            #pragma unroll
            for (int vi = 0; vi < 2; ++vi) {
                if (vi < myCnt) {
                    const int lt = myBase + vi;
                    #pragma unroll
                    for (int ft = 0; ft < 4; ++ft) {
                        const f32x4 a = (k == 1) ? acc1[vi][ft] : acc2[vi][ft];
                        #pragma unroll
                        for (int reg = 0; reg < 4; ++reg) {
                            const int vl = lt * 16 + 4 * q + reg;
                            const int v = v0 + vl;
                            float val = 0.f;
                            if (v < V) {
                                const float cc = dbuf[vl];
                                const float dc = ((k == 1) ? cc : (2.0f * cc * cc - 1.0f)) * adb[vl];
                                val = a[reg] + dc * xp[v * F + 16 * ft + ln];
                            }
                            ys[vl * 72 + 16 * ft + ln] = f2bf(val);
                        }
                    }
                }
            }
        }
        for (int idx = tid; idx < 512; idx += 256) {
            const int fo = idx >> 3, ch = idx & 7;
            *(u16x8*)&ThS[fo * 72 + 8 * ch] =
                *(const u16x8*)&thT[k * 4096 + fo * 64 + 8 * ch];
        }
        __syncthreads();
        #pragma unroll
        for (int vi = 0; vi < 2; ++vi) {
            if (vi < myCnt) {
                const int vrow = (myBase + vi) * 16 + ln;
                #pragma unroll
                for (int ks = 0; ks < 2; ++ks) {
                    const short8 af = *(const short8*)&ys[vrow * 72 + 32 * ks + 8 * q];
                    #pragma unroll
                    for (int fot = 0; fot < 4; ++fot) {
                        const short8 bf = *(const short8*)&ThS[(16 * fot + ln) * 72 + 32 * ks + 8 * q];
                        ot[vi][fot] = __builtin_amdgcn_mfma_f32_16x16x32_bf16(af, bf, ot[vi][fot], 0, 0, 0);
                    }
                }
            }
        }
    }

    // ---- relu + store ----
    #pragma unroll
    for (int vi = 0; vi < 2; ++vi) {
        if (vi < myCnt) {
            const int lt = myBase + vi;
            #pragma unroll
            for (int fot = 0; fot < 4; ++fot) {
                #pragma unroll
                for (int reg = 0; reg < 4; ++reg) {
                    const int v = v0 + lt * 16 + 4 * q + reg;
                    if (v < V)
                        op[v * F + 16 * fot + ln] = fmaxf(ot[vi][fot][reg], 0.f);
                }
            }
        }
    }
}

} // namespace

extern "C" void kernel_launch(void* const* d_in, const int* in_sizes, int n_in,
                              void* d_out, int out_size, void* d_ws, size_t ws_size,
                              hipStream_t stream) {
    const float* x     = (const float*)d_in[0];
    const float* Att   = (const float*)d_in[1];
    const float* S     = (const float*)d_in[2];
    const float* Theta = (const float*)d_in[3];
    float* out         = (float*)d_out;

    char* ws = (char*)d_ws;
    _Float16* Mc        = (_Float16*)(ws + WS_MC);
    _Float16* xTf       = (_Float16*)(ws + WS_XTF);
    _Float16* attF      = (_Float16*)(ws + WS_ATTF);
    unsigned short* thT = (unsigned short*)(ws + WS_THT);
    float* sdiag        = (float*)(ws + WS_SD);
    float* adiag        = (float*)(ws + WS_ADG);

    hipLaunchKernelGGL(prep_all, dim3(NT / 2, 30), dim3(256), 0, stream,
                       S, Att, x, Theta, Mc, attF, xTf, thT, sdiag, adiag);
    hipLaunchKernelGGL(cheb_stream, dim3(2 * NT), dim3(256), 0, stream,
                       x, Mc, attF, sdiag, adiag, thT, xTf, out);
}